// Round 7
// baseline (599.731 us; speedup 1.0000x reference)
//
#include <hip/hip_runtime.h>
#include <math.h>

#define CIN   96
#define HW_IN 3969     // 63*63
#define WIN   63
#define COUT  256
#define NPIX  900      // 30*30
#define WO    30
#define KTOT  2400     // CIN*5*5
#define NB    128
#define KSTEPS 75      // KTOT/32
#define AGG_OFF 65536
#define AGG_BYTES ((size_t)NB * KSTEPS * 16384)   // 157,286,400 B

typedef short bf16x8 __attribute__((ext_vector_type(8)));
typedef float f32x4  __attribute__((ext_vector_type(4)));
typedef __attribute__((address_space(1))) const void gas_t;
typedef __attribute__((address_space(3))) void las_t;

// hardware packed f32->bf16 (RNE), 2 values per instruction
__device__ __forceinline__ unsigned pk2(float lo, float hi) {
  unsigned r;
  asm("v_cvt_pk_bf16_f32 %0, %1, %2" : "=v"(r) : "v"(lo), "v"(hi));
  return r;
}

// ---- Stage 1: per-(b,ci) global average pool over 63x63 ----
__global__ __launch_bounds__(256) void pool_kernel(const float* __restrict__ x,
                                                   float* __restrict__ pooled) {
  const int ci = blockIdx.x;
  const int b  = blockIdx.y;
  const float* xc = x + ((size_t)b * CIN + ci) * HW_IN;
  const int tid = threadIdx.x, lane = tid & 63, wv = tid >> 6;
  float s = 0.f;
  const int head = (4 - (ci & 3)) & 3;
  if (tid < head) s += xc[tid];
  const float4* x4 = (const float4*)(xc + head);
  const int n4 = (HW_IN - head) >> 2;
  for (int i = tid; i < n4; i += 256) { float4 v = x4[i]; s += (v.x + v.y) + (v.z + v.w); }
  const int done = head + (n4 << 2);
  if (tid < HW_IN - done) s += xc[done + tid];
  #pragma unroll
  for (int off = 32; off > 0; off >>= 1) s += __shfl_xor(s, off, 64);
  __shared__ float part[4];
  if (lane == 0) part[wv] = s;
  __syncthreads();
  if (tid == 0)
    pooled[(size_t)b * CIN + ci] = (part[0] + part[1] + part[2] + part[3]) * (1.0f / HW_IN);
}

// ---- Stage 2 (fallback path only): attention MLP + softmax(logits / 31) ----
__global__ __launch_bounds__(64) void attn_kernel(const float* __restrict__ pooled,
                                                  const float* __restrict__ w1,
                                                  const float* __restrict__ w2,
                                                  float* __restrict__ att) {
  const int b = blockIdx.x;
  const int tid = threadIdx.x;
  __shared__ float hidden[24];
  const float* pb = pooled + (size_t)b * CIN;
  if (tid < 24) {
    float h = 0.f;
    const float* w1r = w1 + tid * CIN;
    for (int ci = 0; ci < CIN; ++ci) h += pb[ci] * w1r[ci];
    hidden[tid] = fmaxf(h, 0.f);
  }
  __syncthreads();
  if (tid == 0) {
    float l0 = 0.f, l1 = 0.f;
    for (int j = 0; j < 24; ++j) { l0 += hidden[j] * w2[j]; l1 += hidden[j] * w2[24 + j]; }
    l0 *= (1.0f / 31.0f); l1 *= (1.0f / 31.0f);
    const float m = fmaxf(l0, l1);
    const float e0 = expf(l0 - m), e1 = expf(l1 - m);
    const float inv = 1.0f / (e0 + e1);
    att[b * 2 + 0] = e0 * inv;
    att[b * 2 + 1] = e1 * inv;
  }
}

// ---- Stage 2+2.5 fused: attention MLP + per-sample aggregated bf16 weights ----
// One block per (ks, 8-sample chunk): wc/we slice preloaded into regs ONCE,
// then 8 sample iterations of fma+pk2+store. L2 reads 614 MB -> 78 MB.
// ks==0 blocks also publish att[] for conv's bias path.
// aggW layout (bitwise identical to prior rounds):
//   tile (b, ks) = 16384 B = [row 0..255][slot 0..3] 16B units,
//   unit (row, slot) = bf16x8 of A[row][ks*32 + 8*(slot ^ ((row>>1)&3)) + 0..7]
__global__ __launch_bounds__(512) void agg_kernel(const float* __restrict__ wc,
                                                  const float* __restrict__ we,
                                                  const float* __restrict__ pooled,
                                                  const float* __restrict__ w1,
                                                  const float* __restrict__ w2,
                                                  float* __restrict__ att,
                                                  unsigned* __restrict__ aggW) {
  const int ks = blockIdx.x;    // 0..74
  const int b0 = blockIdx.y * 8;
  const int tid = threadIdx.x;

  __shared__ float hidS[8][25];
  __shared__ float attS[8][2];

  // inline attention MLP for this block's 8 samples (same op order as attn_kernel)
  if (tid < 192) {
    const int bb = tid / 24, j = tid - bb * 24;
    const float* pb  = pooled + (size_t)(b0 + bb) * CIN;
    const float* w1r = w1 + j * CIN;
    float h = 0.f;
    for (int ci = 0; ci < CIN; ++ci) h += pb[ci] * w1r[ci];
    hidS[bb][j] = fmaxf(h, 0.f);
  }

  // preload weight slice (issued before the barrier; overlaps the MLP)
  const int row0 = tid >> 2, slot = tid & 3;
  const int oct  = slot ^ ((row0 >> 1) & 3);   // same oct for row0 and row0+128
  const float* pc0 = wc + (size_t)row0 * KTOT + ks * 32 + oct * 8;
  const float* pe0 = we + (size_t)row0 * KTOT + ks * 32 + oct * 8;
  const float* pc1 = pc0 + (size_t)128 * KTOT;
  const float* pe1 = pe0 + (size_t)128 * KTOT;
  const float4 c00 = ((const float4*)pc0)[0], c01 = ((const float4*)pc0)[1];
  const float4 e00 = ((const float4*)pe0)[0], e01 = ((const float4*)pe0)[1];
  const float4 c10 = ((const float4*)pc1)[0], c11 = ((const float4*)pc1)[1];
  const float4 e10 = ((const float4*)pe1)[0], e11 = ((const float4*)pe1)[1];

  __syncthreads();
  if (tid < 8) {
    float l0 = 0.f, l1 = 0.f;
    for (int j = 0; j < 24; ++j) { l0 += hidS[tid][j] * w2[j]; l1 += hidS[tid][j] * w2[24 + j]; }
    l0 *= (1.0f / 31.0f); l1 *= (1.0f / 31.0f);
    const float m = fmaxf(l0, l1);
    const float e0 = expf(l0 - m), e1 = expf(l1 - m);
    const float inv = 1.0f / (e0 + e1);
    attS[tid][0] = e0 * inv;
    attS[tid][1] = e1 * inv;
    if (ks == 0) {
      att[(b0 + tid) * 2 + 0] = attS[tid][0];
      att[(b0 + tid) * 2 + 1] = attS[tid][1];
    }
  }
  __syncthreads();

  #pragma unroll 2
  for (int bb = 0; bb < 8; ++bb) {
    const float a0 = attS[bb][0], a1 = attS[bb][1];
    uint4 q0, q1;
    q0.x = pk2(a0 * c00.x + a1 * e00.x, a0 * c00.y + a1 * e00.y);
    q0.y = pk2(a0 * c00.z + a1 * e00.z, a0 * c00.w + a1 * e00.w);
    q0.z = pk2(a0 * c01.x + a1 * e01.x, a0 * c01.y + a1 * e01.y);
    q0.w = pk2(a0 * c01.z + a1 * e01.z, a0 * c01.w + a1 * e01.w);
    q1.x = pk2(a0 * c10.x + a1 * e10.x, a0 * c10.y + a1 * e10.y);
    q1.y = pk2(a0 * c10.z + a1 * e10.z, a0 * c10.w + a1 * e10.w);
    q1.z = pk2(a0 * c11.x + a1 * e11.x, a0 * c11.y + a1 * e11.y);
    q1.w = pk2(a0 * c11.z + a1 * e11.z, a0 * c11.w + a1 * e11.w);
    unsigned* dst = aggW + (((size_t)(b0 + bb) * KSTEPS + ks) << 12);
    ((uint4*)dst)[tid]       = q0;   // rows 0..127 half
    ((uint4*)dst)[tid + 512] = q1;   // rows 128..255 half
  }
}

// ---- Stage 3: merged implicit GEMM: 512 threads, 256x128 tile/block (R6, unchanged) ----
__global__ __launch_bounds__(512) void conv_pre(
    const float* __restrict__ x,
    const float* __restrict__ bc, const float* __restrict__ be,
    const float* __restrict__ att, const unsigned* __restrict__ aggW,
    float* __restrict__ out) {
  // bijective XCD swizzle over 1024 workgroups
  const int flat = (int)(blockIdx.x + (blockIdx.z << 3));
  const int wg   = ((flat & 7) << 7) | (flat >> 3);
  const int p0 = (wg & 7) * 128;          // pixel tile
  const int b  = wg >> 3;                 // sample

  __shared__ short As[2][256 * 32];       // 2x 16KB, gl_lds image (slot-swizzled)
  __shared__ short Bs[2][128 * 32];       // 2x 8KB, [row][unit ^ ((row>>1)&3)]
  __shared__ int   koffAll[KTOT];
  __shared__ float biasS[COUT];

  const int tid  = threadIdx.x;
  const int wv   = tid >> 6, lane = tid & 63;
  const int quad = lane >> 4, lm = lane & 15;
  const int wm = (wv >> 1) * 64;          // 0,64,128,192
  const int wn = (wv & 1) * 64;           // 0,64

  if (tid < COUT) {
    const float a0 = att[b * 2 + 0], a1 = att[b * 2 + 1];
    biasS[tid] = a0 * bc[tid] + a1 * be[tid];
  }
  for (int k = tid; k < KTOT; k += 512) {
    const int ci = k / 25, r = k - ci * 25;
    const int kh = r / 5,  kw = r - kh * 5;
    koffAll[k] = ci * HW_IN + kh * WIN + kw;
  }

  const int rowT = tid >> 2;              // 0..127: pixel row of B task
  const int oct  = (tid & 3) * 8;         // k-octet
  const int bu   = (tid & 3) ^ ((rowT >> 1) & 3);   // swizzled write unit

  const float* xb = x + (size_t)b * (CIN * HW_IN);
  const int pA = p0 + rowT;
  const int ohA = pA / WO, owA = pA - ohA * WO;
  const bool vA = pA < NPIX;
  const float* xpA = xb + (ohA * 2) * WIN + owA * 2;

  const char* aggB = (const char*)aggW
                   + ((size_t)b * KSTEPS << 14)
                   + (((wv << 7) + lane) << 4);
  const int xoct = quad ^ ((lm >> 1) & 3);   // un-swizzle for fragment reads (A and B)

  const f32x4 zero = {0.f, 0.f, 0.f, 0.f};
  f32x4 acc[4][4];
  #pragma unroll
  for (int i = 0; i < 4; ++i)
    #pragma unroll
    for (int j = 0; j < 4; ++j) acc[i][j] = zero;

  __syncthreads();   // koffAll / biasS ready

  // ---- prologue: stage A(0), B(0) into buffer 0 ----
  {
    __builtin_amdgcn_global_load_lds((gas_t*)aggB, (las_t*)&As[0][wv << 10], 16, 0, 0);
    __builtin_amdgcn_global_load_lds((gas_t*)(aggB + 1024), (las_t*)&As[0][(wv << 10) + 512], 16, 0, 0);
    const int4 ka = *(const int4*)&koffAll[oct];
    const int4 kb = *(const int4*)&koffAll[oct + 4];
    uint4 qa = {0u, 0u, 0u, 0u};
    if (vA) {
      qa.x = pk2(xpA[ka.x], xpA[ka.y]); qa.y = pk2(xpA[ka.z], xpA[ka.w]);
      qa.z = pk2(xpA[kb.x], xpA[kb.y]); qa.w = pk2(xpA[kb.z], xpA[kb.w]);
    }
    *(uint4*)&Bs[0][rowT * 32 + bu * 8] = qa;
  }
  __syncthreads();   // tile 0 resident (implicit vmcnt(0) drains gl_lds)

  for (int ks = 0; ks < KSTEPS - 1; ++ks) {
    const int cur = ks & 1, nxt = cur ^ 1;
    // -- issue stage(ks+1): A direct-to-LDS + B gathers to regs --
    const char* src = aggB + ((size_t)(ks + 1) << 14);
    __builtin_amdgcn_global_load_lds((gas_t*)src, (las_t*)&As[nxt][wv << 10], 16, 0, 0);
    __builtin_amdgcn_global_load_lds((gas_t*)(src + 1024), (las_t*)&As[nxt][(wv << 10) + 512], 16, 0, 0);
    const int k1 = (ks + 1) << 5;
    const int4 ka = *(const int4*)&koffAll[k1 + oct];
    const int4 kb = *(const int4*)&koffAll[k1 + oct + 4];
    float g0 = 0.f, g1 = 0.f, g2 = 0.f, g3 = 0.f, g4 = 0.f, g5 = 0.f, g6 = 0.f, g7 = 0.f;
    if (vA) {
      g0 = xpA[ka.x]; g1 = xpA[ka.y]; g2 = xpA[ka.z]; g3 = xpA[ka.w];
      g4 = xpA[kb.x]; g5 = xpA[kb.y]; g6 = xpA[kb.z]; g7 = xpA[kb.w];
    }
    // -- compute(ks): gather latency hides under ds_read + MFMA --
    bf16x8 af[4], bfv[4];
    #pragma unroll
    for (int i = 0; i < 4; ++i)
      af[i] = *(const bf16x8*)&As[cur][(wm + i * 16 + lm) * 32 + xoct * 8];
    #pragma unroll
    for (int j = 0; j < 4; ++j)
      bfv[j] = *(const bf16x8*)&Bs[cur][(wn + j * 16 + lm) * 32 + xoct * 8];
    #pragma unroll
    for (int i = 0; i < 4; ++i)
      #pragma unroll
      for (int j = 0; j < 4; ++j)
        acc[i][j] = __builtin_amdgcn_mfma_f32_16x16x32_bf16(af[i], bfv[j], acc[i][j], 0, 0, 0);
    // -- publish B(ks+1) --
    uint4 qa;
    qa.x = pk2(g0, g1); qa.y = pk2(g2, g3); qa.z = pk2(g4, g5); qa.w = pk2(g6, g7);
    *(uint4*)&Bs[nxt][rowT * 32 + bu * 8] = qa;
    __syncthreads();   // drains gl_lds (vmcnt 0) + publishes Bs[nxt]
  }

  // ---- epilogue: compute last tile (ks = 74) ----
  {
    const int cur = (KSTEPS - 1) & 1;
    bf16x8 af[4], bfv[4];
    #pragma unroll
    for (int i = 0; i < 4; ++i)
      af[i] = *(const bf16x8*)&As[cur][(wm + i * 16 + lm) * 32 + xoct * 8];
    #pragma unroll
    for (int j = 0; j < 4; ++j)
      bfv[j] = *(const bf16x8*)&Bs[cur][(wn + j * 16 + lm) * 32 + xoct * 8];
    #pragma unroll
    for (int i = 0; i < 4; ++i)
      #pragma unroll
      for (int j = 0; j < 4; ++j)
        acc[i][j] = __builtin_amdgcn_mfma_f32_16x16x32_bf16(af[i], bfv[j], acc[i][j], 0, 0, 0);
  }

  // ---- store: D row = quad*4 + r, col = lm ----
  float* outb = out + (size_t)b * COUT * NPIX;
  #pragma unroll
  for (int j = 0; j < 4; ++j) {
    const int p = p0 + wn + j * 16 + lm;
    if (p < NPIX) {
      #pragma unroll
      for (int i = 0; i < 4; ++i) {
        #pragma unroll
        for (int r = 0; r < 4; ++r) {
          const int m = wm + i * 16 + quad * 4 + r;
          outb[(size_t)m * NPIX + p] = acc[i][j][r] + biasS[m];
        }
      }
    }
  }
}

// ---- fallback (workspace too small): in-kernel aggregation, 2-barrier loop ----
__global__ __launch_bounds__(256) void conv_fb(
    const float* __restrict__ x,
    const float* __restrict__ wc, const float* __restrict__ we,
    const float* __restrict__ bc, const float* __restrict__ be,
    const float* __restrict__ att, float* __restrict__ out) {
  const int flat = (int)(blockIdx.x + (blockIdx.y << 3) + (blockIdx.z << 4));
  const int wg   = ((flat & 7) << 8) | (flat >> 3);
  const int p0 = (wg & 7) * 128;
  const int m0 = ((wg >> 3) & 1) * 128;
  const int b  = wg >> 4;

  __shared__ short As[128 * 40];
  __shared__ short Bs[128][40];
  __shared__ int   koffAll[KTOT];
  __shared__ float biasS[128];

  const int tid  = threadIdx.x;
  const int wv   = tid >> 6, lane = tid & 63;
  const int quad = lane >> 4, lm = lane & 15;
  const int wm = (wv >> 1) * 64;
  const int wn = (wv & 1) * 64;

  const float a0 = att[b * 2 + 0];
  const float a1 = att[b * 2 + 1];

  if (tid < 128) biasS[tid] = a0 * bc[m0 + tid] + a1 * be[m0 + tid];
  for (int k = tid; k < KTOT; k += 256) {
    const int ci = k / 25, r = k - ci * 25;
    const int kh = r / 5,  kw = r - kh * 5;
    koffAll[k] = ci * HW_IN + kh * WIN + kw;
  }

  const int rowT = tid >> 2;
  const int oct  = (tid & 3) * 8;

  const float* xb = x + (size_t)b * (CIN * HW_IN);
  const int pA = p0 + rowT, pB = p0 + rowT + 64;
  const int ohA = pA / WO, owA = pA - ohA * WO;
  const int ohB = pB / WO, owB = pB - ohB * WO;
  const bool vA = pA < NPIX, vB = pB < NPIX;
  const float* xpA = xb + (ohA * 2) * WIN + owA * 2;
  const float* xpB = xb + (ohB * 2) * WIN + owB * 2;

  const float* wcr0 = wc + (size_t)(m0 + rowT) * KTOT + oct;
  const float* wer0 = we + (size_t)(m0 + rowT) * KTOT + oct;

  const f32x4 zero = {0.f, 0.f, 0.f, 0.f};
  f32x4 acc[4][4];
  #pragma unroll
  for (int i = 0; i < 4; ++i)
    #pragma unroll
    for (int j = 0; j < 4; ++j) acc[i][j] = zero;

  for (int k0 = 0; k0 < KTOT; k0 += 32) {
    __syncthreads();
    #pragma unroll
    for (int t = 0; t < 2; ++t) {
      const float4* pc = (const float4*)(wcr0 + (size_t)t * 64 * KTOT + k0);
      const float4* pe = (const float4*)(wer0 + (size_t)t * 64 * KTOT + k0);
      float4 c0 = pc[0], c1 = pc[1];
      float4 e0 = pe[0], e1 = pe[1];
      uint4 q;
      q.x = pk2(a0 * c0.x + a1 * e0.x, a0 * c0.y + a1 * e0.y);
      q.y = pk2(a0 * c0.z + a1 * e0.z, a0 * c0.w + a1 * e0.w);
      q.z = pk2(a0 * c1.x + a1 * e1.x, a0 * c1.y + a1 * e1.y);
      q.w = pk2(a0 * c1.z + a1 * e1.z, a0 * c1.w + a1 * e1.w);
      *(uint4*)&As[(rowT + t * 64) * 40 + oct] = q;
    }
    const int4 ka = *(const int4*)&koffAll[k0 + oct];
    const int4 kb = *(const int4*)&koffAll[k0 + oct + 4];
    {
      uint4 q = {0u, 0u, 0u, 0u};
      if (vA) {
        q.x = pk2(xpA[ka.x], xpA[ka.y]); q.y = pk2(xpA[ka.z], xpA[ka.w]);
        q.z = pk2(xpA[kb.x], xpA[kb.y]); q.w = pk2(xpA[kb.z], xpA[kb.w]);
      }
      *(uint4*)&Bs[rowT][oct] = q;
    }
    {
      uint4 q = {0u, 0u, 0u, 0u};
      if (vB) {
        q.x = pk2(xpB[ka.x], xpB[ka.y]); q.y = pk2(xpB[ka.z], xpB[ka.w]);
        q.z = pk2(xpB[kb.x], xpB[kb.y]); q.w = pk2(xpB[kb.z], xpB[kb.w]);
      }
      *(uint4*)&Bs[rowT + 64][oct] = q;
    }
    __syncthreads();
    bf16x8 af[4], bfv[4];
    #pragma unroll
    for (int i = 0; i < 4; ++i) af[i]  = *(const bf16x8*)&As[(wm + i * 16 + lm) * 40 + quad * 8];
    #pragma unroll
    for (int j = 0; j < 4; ++j) bfv[j] = *(const bf16x8*)&Bs[wn + j * 16 + lm][quad * 8];
    #pragma unroll
    for (int i = 0; i < 4; ++i)
      #pragma unroll
      for (int j = 0; j < 4; ++j)
        acc[i][j] = __builtin_amdgcn_mfma_f32_16x16x32_bf16(af[i], bfv[j], acc[i][j], 0, 0, 0);
  }

  float* outb = out + ((size_t)b * COUT + m0) * NPIX;
  #pragma unroll
  for (int j = 0; j < 4; ++j) {
    const int p = p0 + wn + j * 16 + lm;
    if (p < NPIX) {
      #pragma unroll
      for (int i = 0; i < 4; ++i) {
        #pragma unroll
        for (int r = 0; r < 4; ++r) {
          const int m = wm + i * 16 + quad * 4 + r;
          outb[(size_t)m * NPIX + p] = acc[i][j][r] + biasS[m];
        }
      }
    }
  }
}

extern "C" void kernel_launch(void* const* d_in, const int* in_sizes, int n_in,
                              void* d_out, int out_size, void* d_ws, size_t ws_size,
                              hipStream_t stream) {
  (void)in_sizes; (void)n_in; (void)out_size;
  const float* x  = (const float*)d_in[0];
  const float* wc = (const float*)d_in[1];
  const float* bc = (const float*)d_in[2];
  const float* we = (const float*)d_in[3];
  const float* be = (const float*)d_in[4];
  const float* w1 = (const float*)d_in[5];
  const float* w2 = (const float*)d_in[6];
  float* out = (float*)d_out;

  float* att    = (float*)d_ws;    // 256 floats
  float* pooled = att + 256;       // 12288 floats (ends < 64KB)
  unsigned* aggW = (unsigned*)((char*)d_ws + AGG_OFF);

  pool_kernel<<<dim3(CIN, NB), 256, 0, stream>>>(x, pooled);

  if (ws_size >= AGG_OFF + AGG_BYTES) {
    // agg computes att inline (ks==0 blocks publish it) -> attn kernel removed
    agg_kernel<<<dim3(KSTEPS, 16), 512, 0, stream>>>(wc, we, pooled, w1, w2, att, aggW);
    conv_pre<<<dim3(8, 1, NB), 512, 0, stream>>>(x, bc, be, att, aggW, out);
  } else {
    attn_kernel<<<NB, 64, 0, stream>>>(pooled, w1, w2, att);
    conv_fb<<<dim3(8, 2, NB), 256, 0, stream>>>(x, wc, we, bc, be, att, out);
  }
}